// Round 4
// baseline (248.124 us; speedup 1.0000x reference)
//
#include <hip/hip_runtime.h>
#include <math.h>

#define BB 4
#define HH 8
#define NN 2048
#define DD 64
#define KTOP 16
#define CUT_MARGIN 1e-3f

typedef _Float16 half_t;
typedef __attribute__((ext_vector_type(8))) _Float16 half8;
typedef __attribute__((ext_vector_type(4))) float floatx4;

// ---------------------------------------------------------------------------
// Kernel 1: L = (1/64) * sum_{h,d} q.k via f16x3 MFMA (16x16x32_f16), with
// the fp32 -> (hi, lo*2^11) split fused into the staging phase (RNE, matching
// the former split_f16 kernel bit-for-bit, so L is unchanged vs the passing
// round). 128x128 block tile, 4 waves 2x2, each wave 4x4 tiles of 16x16.
// acc1 = hi.hi ; acc2 = hi.lo' + lo'.hi ; L = (acc1 + acc2/2048)/64.
// LDS: 4 arrays of 128x64 f16 (64 KB), XOR-swizzled in 16B units
// (kg ^ (row&7)) -> <=2-way bank conflicts on staging writes and frag reads.
// Writes L into d_out (top-k converts it to the mask in place).
// ---------------------------------------------------------------------------
__global__ __launch_bounds__(256, 2) void gemm_f16x3(const float* __restrict__ q,
                                                     const float* __restrict__ kp,
                                                     float* __restrict__ L) {
    const int b  = blockIdx.z;
    const int i0 = blockIdx.y * 128;
    const int j0 = blockIdx.x * 128;
    const int tid  = threadIdx.x;
    const int wave = tid >> 6, lane = tid & 63;
    const int wr = wave >> 1, wc = wave & 1;
    const int lm = lane & 15, quad = lane >> 4;

    __shared__ __align__(16) half_t Ah[128 * 64];
    __shared__ __align__(16) half_t Al[128 * 64];
    __shared__ __align__(16) half_t Bh[128 * 64];
    __shared__ __align__(16) half_t Bl[128 * 64];

    floatx4 acc1[4][4], acc2[4][4];
#pragma unroll
    for (int tr = 0; tr < 4; ++tr)
#pragma unroll
        for (int tc = 0; tc < 4; ++tc) {
            acc1[tr][tc] = (floatx4)0.0f;
            acc2[tr][tc] = (floatx4)0.0f;
        }

    for (int h = 0; h < HH; ++h) {
        const size_t aoff = ((size_t)(b * HH + h) * NN + i0) * DD;
        const size_t boff = ((size_t)(b * HH + h) * NN + j0) * DD;
        __syncthreads();
#pragma unroll
        for (int it = 0; it < 4; ++it) {
            const int un  = it * 256 + tid;   // 0..1023 8-elem units
            const int row = un >> 3;          // 0..127
            const int kg  = un & 7;           // 8-elem unit within row
            const int lidx = row * 64 + ((kg ^ (row & 7)) << 3);
            const float* gq = q  + aoff + row * DD + kg * 8;
            const float* gk = kp + boff + row * DD + kg * 8;
            float qa[8], ka[8];
            *(float4*)&qa[0] = *(const float4*)gq;
            *(float4*)&qa[4] = *(const float4*)(gq + 4);
            *(float4*)&ka[0] = *(const float4*)gk;
            *(float4*)&ka[4] = *(const float4*)(gk + 4);
            half8 qh, ql, kh, kl;
#pragma unroll
            for (int e = 0; e < 8; ++e) {
                half_t hq = (half_t)qa[e];
                half_t hk = (half_t)ka[e];
                qh[e] = hq; ql[e] = (half_t)((qa[e] - (float)hq) * 2048.0f);
                kh[e] = hk; kl[e] = (half_t)((ka[e] - (float)hk) * 2048.0f);
            }
            *(half8*)&Ah[lidx] = qh;
            *(half8*)&Al[lidx] = ql;
            *(half8*)&Bh[lidx] = kh;
            *(half8*)&Bl[lidx] = kl;
        }
        __syncthreads();

#pragma unroll
        for (int ks = 0; ks < 2; ++ks) {
            half8 ah[4], al[4], bh[4], bl[4];
            const int unit = ks * 4 + quad;   // 16B unit index in k
#pragma unroll
            for (int t = 0; t < 4; ++t) {
                const int am = wr * 64 + t * 16 + lm;
                const int bm = wc * 64 + t * 16 + lm;
                const int ai = am * 64 + ((unit ^ (am & 7)) << 3);
                const int bi = bm * 64 + ((unit ^ (bm & 7)) << 3);
                ah[t] = *(const half8*)&Ah[ai];
                al[t] = *(const half8*)&Al[ai];
                bh[t] = *(const half8*)&Bh[bi];
                bl[t] = *(const half8*)&Bl[bi];
            }
#pragma unroll
            for (int tr = 0; tr < 4; ++tr)
#pragma unroll
                for (int tc = 0; tc < 4; ++tc) {
                    acc1[tr][tc] = __builtin_amdgcn_mfma_f32_16x16x32_f16(
                        ah[tr], bh[tc], acc1[tr][tc], 0, 0, 0);
                    acc2[tr][tc] = __builtin_amdgcn_mfma_f32_16x16x32_f16(
                        ah[tr], bl[tc], acc2[tr][tc], 0, 0, 0);
                    acc2[tr][tc] = __builtin_amdgcn_mfma_f32_16x16x32_f16(
                        al[tr], bh[tc], acc2[tr][tc], 0, 0, 0);
                }
        }
    }

    const float s1 = 0.015625f;            // 1/64
    const float s2 = 0.015625f / 2048.0f;  // undo lo scaling
#pragma unroll
    for (int tr = 0; tr < 4; ++tr)
#pragma unroll
        for (int r = 0; r < 4; ++r) {
            const int grow = i0 + wr * 64 + tr * 16 + quad * 4 + r;
            float* Lp = L + ((size_t)b * NN + grow) * NN + j0 + wc * 64 + lm;
#pragma unroll
            for (int tc = 0; tc < 4; ++tc)
                Lp[tc * 16] = acc1[tr][tc][r] * s1 + acc2[tr][tc][r] * s2;
        }
}

// ---------------------------------------------------------------------------
// Kernel 2: one wave per row. z32 prefilter (cheap hw-log gumbel) -> cutoff
// (16th of 64 lane-maxima via bitonic, minus margin) -> ballot-prefix
// candidate gather -> zero row -> f64 refine -> scatter ones.
// Margin analysis: f32-vs-f64 epsilon divergence log(1+1e-9/w) exceeds 1e-3
// only for g>13.8, and such elements are ~9+ units above the threshold, so
// the candidate superset is preserved; the f64 refine decides the mask.
// ---------------------------------------------------------------------------
__device__ __forceinline__ unsigned long long flip64(double x) {
    unsigned long long v = (unsigned long long)__double_as_longlong(x);
    return v ^ ((0ULL - (v >> 63)) | 0x8000000000000000ULL);
}
__device__ __forceinline__ double unflip64(unsigned long long k) {
    unsigned long long v = (k >> 63) ? (k ^ 0x8000000000000000ULL) : ~k;
    return __longlong_as_double((long long)v);
}

__global__ __launch_bounds__(256, 3) void topk_mask(float* LM,   // in-place
                                                    const float* __restrict__ u) {
    const int wave = threadIdx.x >> 6, lane = threadIdx.x & 63;
    const int row = blockIdx.x * 4 + wave;
    float* lrow = LM + (size_t)row * NN;
    const float* urow = u + (size_t)row * NN;

    __shared__ int   s_idx[4][64];
    __shared__ float s_L[4][64];

    // phase 0: load row, compute z32
    float Lv[32], z[32];
#pragma unroll
    for (int e = 0; e < 8; ++e) {
        float4 lv = *(const float4*)(lrow + e * 256 + lane * 4);
        float4 uv = *(const float4*)(urow + e * 256 + lane * 4);
        float ls[4] = {lv.x, lv.y, lv.z, lv.w};
        float us[4] = {uv.x, uv.y, uv.z, uv.w};
#pragma unroll
        for (int s = 0; s < 4; ++s) {
            float t = us[s] + 1e-9f;
            float w = -__logf(t);            // hw v_log_f32: ~1ulp relative
            float g = -__logf(w + 1e-9f);
            Lv[e * 4 + s] = ls[s];
            z[e * 4 + s]  = ls[s] + g;
        }
    }

    // phase 1: cutoff = (16th largest of 64 lane-maxima) - margin
    float v = z[0];
#pragma unroll
    for (int r = 1; r < 32; ++r) v = fmaxf(v, z[r]);
#pragma unroll
    for (int kS = 2; kS <= 64; kS <<= 1) {
#pragma unroll
        for (int j = kS >> 1; j > 0; j >>= 1) {
            float o = __shfl_xor(v, j, 64);
            bool asc = ((lane & kS) == 0);
            bool lower = ((lane & j) == 0);
            float mn = fminf(v, o), mx = fmaxf(v, o);
            v = (asc == lower) ? mn : mx;
        }
    }
    const float cut = __shfl(v, 48, 64) - CUT_MARGIN;

    // phase 2: ballot-prefix candidate gather; then zero the row
    int c = 0;
#pragma unroll
    for (int r = 0; r < 32; ++r) {
        bool p = (z[r] >= cut);
        unsigned long long m = __ballot(p);
        if (p) {
            int slot = c + __popcll(m & ((1ULL << lane) - 1ULL));
            if (slot < 64) {
                s_idx[wave][slot] = (r >> 2) * 256 + lane * 4 + (r & 3);
                s_L[wave][slot]   = Lv[r];
            }
        }
        c += __popcll(m);
    }
    if (c > 64) c = 64;

    float4 z4 = make_float4(0.f, 0.f, 0.f, 0.f);
#pragma unroll
    for (int e = 0; e < 8; ++e)
        *(float4*)(lrow + e * 256 + lane * 4) = z4;
    __syncthreads();   // drains vmcnt: zero-stores complete before scatter

    // phase 3: f64 refine on candidates, threshold = 16th largest z64
    unsigned long long key = 0xFFFFFFFFFFFFFFFFULL;
    double z64 = 0.0;
    int myidx = -1;
    if (lane < c) {
        myidx = s_idx[wave][lane];
        double uu = (double)urow[myidx] + 1e-9;
        double w  = -log(uu);
        double g  = -log(w + 1e-9);
        z64 = (double)s_L[wave][lane] + g;
        key = flip64(z64);
    }
    const int rounds = c - (KTOP - 1);   // >=1 since c>=16 by construction
    unsigned long long m = 0;
    for (int r = 0; r < rounds; ++r) {
        m = key;
#pragma unroll
        for (int off = 32; off >= 1; off >>= 1) {
            unsigned long long o = __shfl_xor(m, off, 64);
            m = (o < m) ? o : m;
        }
        unsigned long long bm = __ballot(key == m);
        if (lane == __builtin_ctzll(bm)) key = 0xFFFFFFFFFFFFFFFFULL;
    }
    double thresh = unflip64(m);
    if (myidx >= 0) lrow[myidx] = (z64 >= thresh) ? 1.0f : 0.0f;
}

extern "C" void kernel_launch(void* const* d_in, const int* in_sizes, int n_in,
                              void* d_out, int out_size, void* d_ws, size_t ws_size,
                              hipStream_t stream) {
    const float* q = (const float*)d_in[0];
    const float* k = (const float*)d_in[1];
    const float* u = (const float*)d_in[2];
    float* out = (float*)d_out;          // logits scratch, then final mask
    (void)d_ws; (void)ws_size;

    dim3 grid1(NN / 128, NN / 128, BB);
    gemm_f16x3<<<grid1, 256, 0, stream>>>(q, k, out);

    topk_mask<<<(BB * NN) / 4, 256, 0, stream>>>(out, u);
}

// Round 5
// 216.687 us; speedup vs baseline: 1.1451x; 1.1451x over previous
//
#include <hip/hip_runtime.h>
#include <math.h>

#define BB 4
#define HH 8
#define NN 2048
#define DD 64
#define KTOP 16
#define CUT_MARGIN 1e-3f

typedef _Float16 half_t;
typedef __attribute__((ext_vector_type(8))) _Float16 half8;
typedef __attribute__((ext_vector_type(4))) float floatx4;

// async 16B global->LDS copy (hardware scatters lane i at ldsbase + i*16)
__device__ __forceinline__ void gl_lds16(const half_t* g, half_t* l) {
    __builtin_amdgcn_global_load_lds(
        (const __attribute__((address_space(1))) void*)g,
        (__attribute__((address_space(3))) void*)l, 16, 0, 0);
}

// ---------------------------------------------------------------------------
// Kernel 0: split fp32 q,k into f16 hi + f16 (lo*2^11), stored PRE-SWIZZLED:
// output unit (row, kg^(row&7)) = input unit (row, kg)  [16B units, 8/row].
// A linear lane-ordered global_load_lds copy in the GEMM then reproduces the
// swizzled LDS layout (unit kg ^ (row&7)) the frag reads expect.
// RNE split identical to prior passing rounds -> L bit-identical.
// ---------------------------------------------------------------------------
__global__ __launch_bounds__(256) void split_swz(const float* __restrict__ q,
                                                 const float* __restrict__ kk,
                                                 half_t* __restrict__ qhi,
                                                 half_t* __restrict__ qlo,
                                                 half_t* __restrict__ khi,
                                                 half_t* __restrict__ klo) {
    const int uidx = blockIdx.x * 256 + threadIdx.x;  // 16B-unit index
    const int row  = uidx >> 3;                       // global row (b*H*N rows)
    const int kg   = uidx & 7;
    const size_t src = (size_t)uidx * 8;
    const size_t dst = (size_t)row * 64 + (size_t)((kg ^ (row & 7)) << 3);

    float a[8], b[8];
    *(float4*)&a[0] = *(const float4*)(q + src);
    *(float4*)&a[4] = *(const float4*)(q + src + 4);
    *(float4*)&b[0] = *(const float4*)(kk + src);
    *(float4*)&b[4] = *(const float4*)(kk + src + 4);
    half8 qh, ql, kh, kl;
#pragma unroll
    for (int e = 0; e < 8; ++e) {
        half_t hq = (half_t)a[e];
        half_t hk = (half_t)b[e];
        qh[e] = hq; ql[e] = (half_t)((a[e] - (float)hq) * 2048.0f);
        kh[e] = hk; kl[e] = (half_t)((b[e] - (float)hk) * 2048.0f);
    }
    *(half8*)(qhi + dst) = qh;
    *(half8*)(qlo + dst) = ql;
    *(half8*)(khi + dst) = kh;
    *(half8*)(klo + dst) = kl;
}

// ---------------------------------------------------------------------------
// Kernel 1: L = (1/64) * sum_{h,d} q.k via f16x3 MFMA (16x16x32_f16).
// 128x128 tile, 4 waves 2x2, 4x4 16x16 tiles/wave, acc1=hi.hi,
// acc2=hi.lo'+lo'.hi. Staging: wave w copies array w (Ah/Al/Bh/Bl) with 16
// global_load_lds_dwordx4 (1 KB each) -- no VGPR round trip, swizzle baked
// into the pre-swizzled global layout. Frag reads: <=2-way conflicts.
// Writes L into d_out (top-k converts it to the mask in place).
// ---------------------------------------------------------------------------
__global__ __launch_bounds__(256, 2) void gemm_f16x3(const half_t* __restrict__ qhi,
                                                     const half_t* __restrict__ qlo,
                                                     const half_t* __restrict__ khi,
                                                     const half_t* __restrict__ klo,
                                                     float* __restrict__ L) {
    const int b  = blockIdx.z;
    const int i0 = blockIdx.y * 128;
    const int j0 = blockIdx.x * 128;
    const int tid  = threadIdx.x;
    const int wave = __builtin_amdgcn_readfirstlane(tid >> 6);
    const int lane = tid & 63;
    const int wr = wave >> 1, wc = wave & 1;
    const int lm = lane & 15, quad = lane >> 4;

    __shared__ __align__(16) half_t Ah[128 * 64];
    __shared__ __align__(16) half_t Al[128 * 64];
    __shared__ __align__(16) half_t Bh[128 * 64];
    __shared__ __align__(16) half_t Bl[128 * 64];

    // per-lane source offset within a 1KB staging chunk (8 rows x 64 halves)
    const int off0 = (lane >> 3) * 64 + (lane & 7) * 8;

    floatx4 acc1[4][4], acc2[4][4];
#pragma unroll
    for (int tr = 0; tr < 4; ++tr)
#pragma unroll
        for (int tc = 0; tc < 4; ++tc) {
            acc1[tr][tc] = (floatx4)0.0f;
            acc2[tr][tc] = (floatx4)0.0f;
        }

    for (int h = 0; h < HH; ++h) {
        const size_t aoff = ((size_t)(b * HH + h) * NN + i0) * DD;
        const size_t boff = ((size_t)(b * HH + h) * NN + j0) * DD;
        const half_t* gbase;
        half_t* lbase;
        if      (wave == 0) { gbase = qhi + aoff; lbase = Ah; }
        else if (wave == 1) { gbase = qlo + aoff; lbase = Al; }
        else if (wave == 2) { gbase = khi + boff; lbase = Bh; }
        else                { gbase = klo + boff; lbase = Bl; }
        gbase += off0;

        __syncthreads();   // previous compute done before overwriting LDS
#pragma unroll
        for (int i = 0; i < 16; ++i)
            gl_lds16(gbase + i * 512, lbase + i * 512);
        __syncthreads();   // drains vmcnt(0): staging visible

#pragma unroll
        for (int ks = 0; ks < 2; ++ks) {
            half8 ah[4], al[4], bh[4], bl[4];
            const int unit = ks * 4 + quad;   // 16B unit index in k
#pragma unroll
            for (int t = 0; t < 4; ++t) {
                const int am = wr * 64 + t * 16 + lm;
                const int bm = wc * 64 + t * 16 + lm;
                const int ai = am * 64 + ((unit ^ (am & 7)) << 3);
                const int bi = bm * 64 + ((unit ^ (bm & 7)) << 3);
                ah[t] = *(const half8*)&Ah[ai];
                al[t] = *(const half8*)&Al[ai];
                bh[t] = *(const half8*)&Bh[bi];
                bl[t] = *(const half8*)&Bl[bi];
            }
#pragma unroll
            for (int tr = 0; tr < 4; ++tr)
#pragma unroll
                for (int tc = 0; tc < 4; ++tc) {
                    acc1[tr][tc] = __builtin_amdgcn_mfma_f32_16x16x32_f16(
                        ah[tr], bh[tc], acc1[tr][tc], 0, 0, 0);
                    acc2[tr][tc] = __builtin_amdgcn_mfma_f32_16x16x32_f16(
                        ah[tr], bl[tc], acc2[tr][tc], 0, 0, 0);
                    acc2[tr][tc] = __builtin_amdgcn_mfma_f32_16x16x32_f16(
                        al[tr], bh[tc], acc2[tr][tc], 0, 0, 0);
                }
        }
    }

    const float s1 = 0.015625f;            // 1/64
    const float s2 = 0.015625f / 2048.0f;  // undo lo scaling
#pragma unroll
    for (int tr = 0; tr < 4; ++tr)
#pragma unroll
        for (int r = 0; r < 4; ++r) {
            const int grow = i0 + wr * 64 + tr * 16 + quad * 4 + r;
            float* Lp = L + ((size_t)b * NN + grow) * NN + j0 + wc * 64 + lm;
#pragma unroll
            for (int tc = 0; tc < 4; ++tc)
                Lp[tc * 16] = acc1[tr][tc][r] * s1 + acc2[tr][tc][r] * s2;
        }
}

// ---------------------------------------------------------------------------
// Kernel 2: one wave per row. z32 prefilter (hw-log gumbel) -> cutoff (16th of
// 64 lane-maxima via bitonic, minus margin) -> ballot-prefix candidate gather
// -> zero row -> f64 refine -> scatter ones.  (unchanged from R4, passed)
// ---------------------------------------------------------------------------
__device__ __forceinline__ unsigned long long flip64(double x) {
    unsigned long long v = (unsigned long long)__double_as_longlong(x);
    return v ^ ((0ULL - (v >> 63)) | 0x8000000000000000ULL);
}
__device__ __forceinline__ double unflip64(unsigned long long k) {
    unsigned long long v = (k >> 63) ? (k ^ 0x8000000000000000ULL) : ~k;
    return __longlong_as_double((long long)v);
}

__global__ __launch_bounds__(256, 3) void topk_mask(float* LM,   // in-place
                                                    const float* __restrict__ u) {
    const int wave = threadIdx.x >> 6, lane = threadIdx.x & 63;
    const int row = blockIdx.x * 4 + wave;
    float* lrow = LM + (size_t)row * NN;
    const float* urow = u + (size_t)row * NN;

    __shared__ int   s_idx[4][64];
    __shared__ float s_L[4][64];

    float Lv[32], z[32];
#pragma unroll
    for (int e = 0; e < 8; ++e) {
        float4 lv = *(const float4*)(lrow + e * 256 + lane * 4);
        float4 uv = *(const float4*)(urow + e * 256 + lane * 4);
        float ls[4] = {lv.x, lv.y, lv.z, lv.w};
        float us[4] = {uv.x, uv.y, uv.z, uv.w};
#pragma unroll
        for (int s = 0; s < 4; ++s) {
            float t = us[s] + 1e-9f;
            float w = -__logf(t);
            float g = -__logf(w + 1e-9f);
            Lv[e * 4 + s] = ls[s];
            z[e * 4 + s]  = ls[s] + g;
        }
    }

    float v = z[0];
#pragma unroll
    for (int r = 1; r < 32; ++r) v = fmaxf(v, z[r]);
#pragma unroll
    for (int kS = 2; kS <= 64; kS <<= 1) {
#pragma unroll
        for (int j = kS >> 1; j > 0; j >>= 1) {
            float o = __shfl_xor(v, j, 64);
            bool asc = ((lane & kS) == 0);
            bool lower = ((lane & j) == 0);
            float mn = fminf(v, o), mx = fmaxf(v, o);
            v = (asc == lower) ? mn : mx;
        }
    }
    const float cut = __shfl(v, 48, 64) - CUT_MARGIN;

    int c = 0;
#pragma unroll
    for (int r = 0; r < 32; ++r) {
        bool p = (z[r] >= cut);
        unsigned long long m = __ballot(p);
        if (p) {
            int slot = c + __popcll(m & ((1ULL << lane) - 1ULL));
            if (slot < 64) {
                s_idx[wave][slot] = (r >> 2) * 256 + lane * 4 + (r & 3);
                s_L[wave][slot]   = Lv[r];
            }
        }
        c += __popcll(m);
    }
    if (c > 64) c = 64;

    float4 z4 = make_float4(0.f, 0.f, 0.f, 0.f);
#pragma unroll
    for (int e = 0; e < 8; ++e)
        *(float4*)(lrow + e * 256 + lane * 4) = z4;
    __syncthreads();   // zero-stores complete before scatter

    unsigned long long key = 0xFFFFFFFFFFFFFFFFULL;
    double z64 = 0.0;
    int myidx = -1;
    if (lane < c) {
        myidx = s_idx[wave][lane];
        double uu = (double)urow[myidx] + 1e-9;
        double w  = -log(uu);
        double g  = -log(w + 1e-9);
        z64 = (double)s_L[wave][lane] + g;
        key = flip64(z64);
    }
    const int rounds = c - (KTOP - 1);
    unsigned long long m = 0;
    for (int r = 0; r < rounds; ++r) {
        m = key;
#pragma unroll
        for (int off = 32; off >= 1; off >>= 1) {
            unsigned long long o = __shfl_xor(m, off, 64);
            m = (o < m) ? o : m;
        }
        unsigned long long bm = __ballot(key == m);
        if (lane == __builtin_ctzll(bm)) key = 0xFFFFFFFFFFFFFFFFULL;
    }
    double thresh = unflip64(m);
    if (myidx >= 0) lrow[myidx] = (z64 >= thresh) ? 1.0f : 0.0f;
}

extern "C" void kernel_launch(void* const* d_in, const int* in_sizes, int n_in,
                              void* d_out, int out_size, void* d_ws, size_t ws_size,
                              hipStream_t stream) {
    const float* q = (const float*)d_in[0];
    const float* k = (const float*)d_in[1];
    const float* u = (const float*)d_in[2];
    float* out = (float*)d_out;          // logits scratch, then final mask
    const size_t NQ = (size_t)BB * HH * NN * DD;   // 4M elements
    half_t* qhi = (half_t*)d_ws;
    half_t* qlo = qhi + NQ;
    half_t* khi = qlo + NQ;
    half_t* klo = khi + NQ;              // 32 MB total in d_ws

    split_swz<<<(int)(NQ / 8 / 256), 256, 0, stream>>>(q, k, qhi, qlo, khi, klo);

    dim3 grid1(NN / 128, NN / 128, BB);
    gemm_f16x3<<<grid1, 256, 0, stream>>>(qhi, qlo, khi, klo, out);

    topk_mask<<<(BB * NN) / 4, 256, 0, stream>>>(out, u);
}